// Round 3
// baseline (822.944 us; speedup 1.0000x reference)
//
#include <hip/hip_runtime.h>

// AdjointODE: h += dt * ( tanh(h@W1+b1) @ W2 + b2 ), 50 Euler steps.
// BATCH=32768, DIM=128, HID=256.
// ROUND 12: REGISTER-CACHE HALF OF W2 (LDS-BW theory).
// r11 post-mortem: rotation gave only +3%; MfmaUtil(34%)/VALU match static
// demand; missing 42% = LDS waits. Audit: 144 ds_read_b128/wave-step =
// ~1.1 MB/CU/step ~= 10k cyc at ~112 B/cyc/CU achievable -> LDS-read-BW
// bound (weights re-streamed from LDS by every wave every step).
// Fix: cache W2 chunks p=4..7 (32 frags x 4 VGPR = 128 VGPR) in registers
// per wave, loaded once after the barrier. W2 reads are the least-hidable
// (consumed same iteration). Cached chunks consumed in a fully-unrolled
// tail (static reg indices; no dynamic indexing -> no scratch).
// LDS bytes/CU/step -22%. VGPR ~230 of 256 budget (__launch_bounds__(512,2)).
// Spill canary: FETCH ~9.3 MB / WRITE 16 MB; VGPR must stay < 256.
// Else = r11: depth-1 rotated pipeline (mm1(p); mm2(p-1); act(p)),
// fragment-linear weight LDS, 256x512, wave owns 16 rows, h fp32-resident,
// pk2 packing, b1 as accumulator init (TSCALE-folded), b2 via VALU fma.

typedef __attribute__((ext_vector_type(8))) short short8;
typedef __attribute__((ext_vector_type(4))) float float4v;
typedef __attribute__((ext_vector_type(4))) int int4v;

union FB { int4v i; short8 s; };

// LDS map (bytes)
#define W1F_OFF 0        // 64 frags (nt*4+c) x 1 KB = 64 KB
#define W2F_OFF 65536    // 64 frags (p*8+tb) x 1 KB = 64 KB
#define B1_OFF  131072   // f32[256] (TSCALE-folded b1)
#define DT_OFF  132096   // f32[64]
#define LDS_BYTES 132352

#define TSCALE 2.8853900817779268f  // 2/ln2: tanh(x) = 1 - 2/(exp2(x*TSCALE)+1)

__device__ __forceinline__ unsigned rne2(float x) {
  unsigned u = __float_as_uint(x);
  return u + 0x7fffu + ((u >> 16) & 1u);
}

#if __has_builtin(__builtin_amdgcn_cvt_pk_bf16_f32)
__device__ __forceinline__ int pk2(float lo, float hi) {
  return __builtin_bit_cast(int, __builtin_amdgcn_cvt_pk_bf16_f32(lo, hi));
}
#else
__device__ __forceinline__ int pk2(float lo, float hi) {
  return (int)__builtin_amdgcn_perm(rne2(hi), rne2(lo), 0x07060302u);
}
#endif

// B-frag for one 32-K chunk from two C-layout float4 tiles (even, odd).
__device__ __forceinline__ int4v packfrag(float4v e, float4v o) {
  int4v f;
  f.x = pk2(e.x, e.y);
  f.y = pk2(e.z, e.w);
  f.z = pk2(o.x, o.y);
  f.w = pk2(o.z, o.w);
  return f;
}

#define MFMA16(a, b, c) __builtin_amdgcn_mfma_f32_16x16x32_bf16(a, b, c, 0, 0, 0)

extern "C" __global__ __launch_bounds__(512, 2)
void ode_kernel(const float* __restrict__ inp, const float* __restrict__ ts,
                const float* __restrict__ W1, const float* __restrict__ b1,
                const float* __restrict__ W2, const float* __restrict__ b2,
                float* __restrict__ out) {
  __shared__ __align__(16) char ldsb[LDS_BYTES];
  float* b1f = (float*)(ldsb + B1_OFF);
  float* dtf = (float*)(ldsb + DT_OFF);

  const int tid = threadIdx.x;
  const int lane = tid & 63, wave = tid >> 6;
  const int ln = lane & 15;  // batch-row within wave's 16
  const int q = lane >> 4;   // quad
  const int row = blockIdx.x * 128 + wave * 16 + ln;

  // ---- stage W1 frags: pair pi = (fid=nt*4+c)*64 + L; wave covers one frag ----
  #pragma unroll 1
  for (int it = 0; it < 8; it++) {
    const int pi = it * 512 + tid;  // [0, 4096)
    const int fid = pi >> 6, L = pi & 63;
    const int nt = fid >> 2, c = fid & 3;
    const int lf = L & 15, qf = L >> 4;
    const int n = nt * 16 + lf;            // hid index (A-frag m-row)
    const int kb = c * 32 + qf * 4;        // logical dim base
    float v0 = W1[(kb + 0) * 256 + n] * TSCALE;
    float v1 = W1[(kb + 1) * 256 + n] * TSCALE;
    float v2 = W1[(kb + 2) * 256 + n] * TSCALE;
    float v3 = W1[(kb + 3) * 256 + n] * TSCALE;
    float v4 = W1[(kb + 16) * 256 + n] * TSCALE;
    float v5 = W1[(kb + 17) * 256 + n] * TSCALE;
    float v6 = W1[(kb + 18) * 256 + n] * TSCALE;
    float v7 = W1[(kb + 19) * 256 + n] * TSCALE;
    int4v d = {pk2(v0, v1), pk2(v2, v3), pk2(v4, v5), pk2(v6, v7)};
    *(int4v*)(ldsb + W1F_OFF + pi * 16) = d;
  }
  // ---- stage W2 frags: fid = p*8 + tb ----
  #pragma unroll 1
  for (int it = 0; it < 8; it++) {
    const int pi = it * 512 + tid;
    const int fid = pi >> 6, L = pi & 63;
    const int p = fid >> 3, tb = fid & 7;
    const int lf = L & 15, qf = L >> 4;
    const int d_out = tb * 16 + lf;        // output-dim (A-frag m-row)
    const int kb = p * 32 + qf * 4;        // logical hid base
    float v0 = W2[(kb + 0) * 128 + d_out];
    float v1 = W2[(kb + 1) * 128 + d_out];
    float v2 = W2[(kb + 2) * 128 + d_out];
    float v3 = W2[(kb + 3) * 128 + d_out];
    float v4 = W2[(kb + 16) * 128 + d_out];
    float v5 = W2[(kb + 17) * 128 + d_out];
    float v6 = W2[(kb + 18) * 128 + d_out];
    float v7 = W2[(kb + 19) * 128 + d_out];
    int4v d = {pk2(v0, v1), pk2(v2, v3), pk2(v4, v5), pk2(v6, v7)};
    *(int4v*)(ldsb + W2F_OFF + pi * 16) = d;
  }
  if (tid < 256) b1f[tid] = b1[tid] * TSCALE;
  if (tid < 50) dtf[tid] = ts[tid + 1] - ts[tid];

  // ---- b2 resident per-lane (C-layout columns) ----
  float4v b2v[8];
  #pragma unroll
  for (int tb = 0; tb < 8; tb++)
    b2v[tb] = *(const float4v*)&b2[tb * 16 + q * 4];

  // ---- load h: 16x16 C-layout. h4[tb][r] = h[row][tb*16 + q*4 + r] ----
  float4v h4[8];
  #pragma unroll
  for (int tb = 0; tb < 8; tb++)
    h4[tb] = *(const float4v*)&inp[row * 128 + tb * 16 + q * 4];

  __syncthreads();  // the only barrier

  // per-lane frag base pointers (reads: base + fid*64 int4vs + immediate)
  const int4v* w1f = (const int4v*)(ldsb + W1F_OFF) + lane;
  const int4v* w2f = (const int4v*)(ldsb + W2F_OFF) + lane;

  // ---- register-cache W2 chunks p=4..7 (32 frags, 128 VGPR), read once ----
  FB w2c[32];
  #pragma unroll
  for (int i = 0; i < 32; i++)
    w2c[i].i = w2f[(32 + i) * 64];

  #pragma unroll 1
  for (int s = 0; s < 50; s++) {
    const float dt = dtf[s];
    const float m2dt = -2.0f * dt;

    // ---- state -> 4 B-frags (pure register packing) ----
    FB hb[4];
    #pragma unroll
    for (int kc = 0; kc < 4; kc++)
      hb[kc].i = packfrag(h4[2 * kc], h4[2 * kc + 1]);

    // ---- rotated depth-1 pipeline over 8 hid-pair chunks ----
    // prologue: mm1(0) + act(0) -> af
    FB af;
    {
      FB wA[4], wB[4];
      #pragma unroll
      for (int c = 0; c < 4; c++) {
        wA[c].i = w1f[(0 * 4 + c) * 64];
        wB[c].i = w1f[(1 * 4 + c) * 64];
      }
      float4v g0 = *(const float4v*)&b1f[0 * 16 + q * 4];
      float4v g1 = *(const float4v*)&b1f[1 * 16 + q * 4];
      #pragma unroll
      for (int c = 0; c < 4; c++) {
        g0 = MFMA16(wA[c].s, hb[c].s, g0);
        g1 = MFMA16(wB[c].s, hb[c].s, g1);
      }
      float4v a0, a1;
      #pragma unroll
      for (int r = 0; r < 4; r++) {
        a0[r] = fmaf(__builtin_amdgcn_rcpf(__builtin_amdgcn_exp2f(g0[r]) + 1.0f), m2dt, dt);
        a1[r] = fmaf(__builtin_amdgcn_rcpf(__builtin_amdgcn_exp2f(g1[r]) + 1.0f), m2dt, dt);
      }
      af.i = packfrag(a0, a1);
    }

    // steady A: p=1..4, mm2(p-1) chunks 0..3 stream from LDS (runtime loop ok)
    #pragma unroll 1
    for (int p = 1; p <= 4; p++) {
      const int nt0 = 2 * p, nt1 = 2 * p + 1;
      FB wA[4], wB[4];
      #pragma unroll
      for (int c = 0; c < 4; c++) {
        wA[c].i = w1f[(nt0 * 4 + c) * 64];
        wB[c].i = w1f[(nt1 * 4 + c) * 64];
      }
      float4v g0 = *(const float4v*)&b1f[nt0 * 16 + q * 4];
      float4v g1 = *(const float4v*)&b1f[nt1 * 16 + q * 4];
      #pragma unroll
      for (int c = 0; c < 4; c++) {
        g0 = MFMA16(wA[c].s, hb[c].s, g0);
        g1 = MFMA16(wB[c].s, hb[c].s, g1);
      }
      {
        FB w2r[8];
        #pragma unroll
        for (int tb = 0; tb < 8; tb++)
          w2r[tb].i = w2f[((p - 1) * 8 + tb) * 64];
        #pragma unroll
        for (int tb = 0; tb < 8; tb++)
          h4[tb] = MFMA16(w2r[tb].s, af.s, h4[tb]);
      }
      float4v a0, a1;
      #pragma unroll
      for (int r = 0; r < 4; r++) {
        a0[r] = fmaf(__builtin_amdgcn_rcpf(__builtin_amdgcn_exp2f(g0[r]) + 1.0f), m2dt, dt);
        a1[r] = fmaf(__builtin_amdgcn_rcpf(__builtin_amdgcn_exp2f(g1[r]) + 1.0f), m2dt, dt);
      }
      af.i = packfrag(a0, a1);
    }

    // steady B: p=5..7 FULLY UNROLLED, mm2(p-1) chunks 4..6 from registers
    // (static w2c indices only — dynamic indexing would spill to scratch)
    #pragma unroll
    for (int p = 5; p <= 7; p++) {
      const int nt0 = 2 * p, nt1 = 2 * p + 1;
      FB wA[4], wB[4];
      #pragma unroll
      for (int c = 0; c < 4; c++) {
        wA[c].i = w1f[(nt0 * 4 + c) * 64];
        wB[c].i = w1f[(nt1 * 4 + c) * 64];
      }
      float4v g0 = *(const float4v*)&b1f[nt0 * 16 + q * 4];
      float4v g1 = *(const float4v*)&b1f[nt1 * 16 + q * 4];
      #pragma unroll
      for (int c = 0; c < 4; c++) {
        g0 = MFMA16(wA[c].s, hb[c].s, g0);
        g1 = MFMA16(wB[c].s, hb[c].s, g1);
      }
      #pragma unroll
      for (int tb = 0; tb < 8; tb++)
        h4[tb] = MFMA16(w2c[(p - 5) * 8 + tb].s, af.s, h4[tb]);
      float4v a0, a1;
      #pragma unroll
      for (int r = 0; r < 4; r++) {
        a0[r] = fmaf(__builtin_amdgcn_rcpf(__builtin_amdgcn_exp2f(g0[r]) + 1.0f), m2dt, dt);
        a1[r] = fmaf(__builtin_amdgcn_rcpf(__builtin_amdgcn_exp2f(g1[r]) + 1.0f), m2dt, dt);
      }
      af.i = packfrag(a0, a1);
    }

    // epilogue: mm2(7) from registers
    #pragma unroll
    for (int tb = 0; tb < 8; tb++)
      h4[tb] = MFMA16(w2c[24 + tb].s, af.s, h4[tb]);

    // ---- h += dt * b2 ----
    #pragma unroll
    for (int tb = 0; tb < 8; tb++)
      #pragma unroll
      for (int r = 0; r < 4; r++)
        h4[tb][r] = fmaf(dt, b2v[tb][r], h4[tb][r]);
  }

  // ---- store ----
  #pragma unroll
  for (int tb = 0; tb < 8; tb++)
    *(float4v*)&out[row * 128 + tb * 16 + q * 4] = h4[tb];
}

extern "C" void kernel_launch(void* const* d_in, const int* in_sizes, int n_in,
                              void* d_out, int out_size, void* d_ws, size_t ws_size,
                              hipStream_t stream) {
  const float* inp = (const float*)d_in[0];
  const float* ts  = (const float*)d_in[1];
  const float* W1  = (const float*)d_in[2];
  const float* b1  = (const float*)d_in[3];
  const float* W2  = (const float*)d_in[4];
  const float* b2  = (const float*)d_in[5];
  hipLaunchKernelGGL(ode_kernel, dim3(256), dim3(512), 0, stream,
                     inp, ts, W1, b1, W2, b2, (float*)d_out);
}

// Round 4
// 406.207 us; speedup vs baseline: 2.0259x; 2.0259x over previous
//
#include <hip/hip_runtime.h>

// AdjointODE: h += dt * ( tanh(h@W1+b1) @ W2 + b2 ), 50 Euler steps.
// BATCH=32768, DIM=128, HID=256.
// ROUND 13: 32 ROWS/WAVE (two B-groups) -> HALVE LDS TRAFFIC PER FLOP.
// Evidence chain: r11's 1152 ds_read_b128/CU/step x ~12cyc = 13.8k cyc
// ~= measured 13.3k cyc/step -> LDS-issue-bound. r12's register cache
// hit the archVGPR/AGPR split wall (compiler pegs archVGPR=128 at
// 2 waves/SIMD; ds_read dests must be archVGPR -> spill).
// This round: each wave owns 32 batch rows as TWO 16-row B-groups.
// Every weight frag read from LDS feeds TWO MFMAs (one per group):
// LDS reads/CU/step 1152 -> 576 (~5-7k cyc) vs MFMA 4.1k cyc.
// Same 16x16x32 intrinsic, same verified frag layouts (zero layout risk).
// Block = 256 thr (4 waves x 32 rows = 128 rows), grid 256 -> all CUs.
// 1 wave/SIMD: TLP was never covering the LDS wall; ILP + long MFMA
// shadows do the hiding. __launch_bounds__(256,1) -> full 512-reg file,
// ~230 live regs fits archVGPR=256 comfortably.
// Spill canary: FETCH ~9.3 MB / WRITE 16 MB; VGPR < 256; conflicts 0.
// Else = r11: depth-1 rotated pipeline (mm1(p); mm2(p-1); act(p)),
// fragment-linear weight LDS, h fp32-resident, pk2 packing, b1 as
// accumulator init (TSCALE-folded), b2 via VALU fma.

typedef __attribute__((ext_vector_type(8))) short short8;
typedef __attribute__((ext_vector_type(4))) float float4v;
typedef __attribute__((ext_vector_type(4))) int int4v;

union FB { int4v i; short8 s; };

// LDS map (bytes)
#define W1F_OFF 0        // 64 frags (nt*4+c) x 1 KB = 64 KB
#define W2F_OFF 65536    // 64 frags (p*8+tb) x 1 KB = 64 KB
#define B1_OFF  131072   // f32[256] (TSCALE-folded b1)
#define DT_OFF  132096   // f32[64]
#define LDS_BYTES 132352

#define TSCALE 2.8853900817779268f  // 2/ln2: tanh(x) = 1 - 2/(exp2(x*TSCALE)+1)

__device__ __forceinline__ unsigned rne2(float x) {
  unsigned u = __float_as_uint(x);
  return u + 0x7fffu + ((u >> 16) & 1u);
}

#if __has_builtin(__builtin_amdgcn_cvt_pk_bf16_f32)
__device__ __forceinline__ int pk2(float lo, float hi) {
  return __builtin_bit_cast(int, __builtin_amdgcn_cvt_pk_bf16_f32(lo, hi));
}
#else
__device__ __forceinline__ int pk2(float lo, float hi) {
  return (int)__builtin_amdgcn_perm(rne2(hi), rne2(lo), 0x07060302u);
}
#endif

// B-frag for one 32-K chunk from two C-layout float4 tiles (even, odd).
__device__ __forceinline__ int4v packfrag(float4v e, float4v o) {
  int4v f;
  f.x = pk2(e.x, e.y);
  f.y = pk2(e.z, e.w);
  f.z = pk2(o.x, o.y);
  f.w = pk2(o.z, o.w);
  return f;
}

#define MFMA16(a, b, c) __builtin_amdgcn_mfma_f32_16x16x32_bf16(a, b, c, 0, 0, 0)

extern "C" __global__ __launch_bounds__(256, 1)
void ode_kernel(const float* __restrict__ inp, const float* __restrict__ ts,
                const float* __restrict__ W1, const float* __restrict__ b1,
                const float* __restrict__ W2, const float* __restrict__ b2,
                float* __restrict__ out) {
  __shared__ __align__(16) char ldsb[LDS_BYTES];
  float* b1f = (float*)(ldsb + B1_OFF);
  float* dtf = (float*)(ldsb + DT_OFF);

  const int tid = threadIdx.x;
  const int lane = tid & 63, wave = tid >> 6;
  const int ln = lane & 15;  // batch-row within group
  const int q = lane >> 4;   // quad
  const int rowa = blockIdx.x * 128 + wave * 32 + ln;  // group A row
  const int rowb = rowa + 16;                          // group B row

  // ---- stage W1 frags: pi = (fid=nt*4+c)*64 + L; 256 thr x 16 iters ----
  #pragma unroll 1
  for (int it = 0; it < 16; it++) {
    const int pi = it * 256 + tid;  // [0, 4096)
    const int fid = pi >> 6, L = pi & 63;
    const int nt = fid >> 2, c = fid & 3;
    const int lf = L & 15, qf = L >> 4;
    const int n = nt * 16 + lf;            // hid index (A-frag m-row)
    const int kb = c * 32 + qf * 4;        // logical dim base
    float v0 = W1[(kb + 0) * 256 + n] * TSCALE;
    float v1 = W1[(kb + 1) * 256 + n] * TSCALE;
    float v2 = W1[(kb + 2) * 256 + n] * TSCALE;
    float v3 = W1[(kb + 3) * 256 + n] * TSCALE;
    float v4 = W1[(kb + 16) * 256 + n] * TSCALE;
    float v5 = W1[(kb + 17) * 256 + n] * TSCALE;
    float v6 = W1[(kb + 18) * 256 + n] * TSCALE;
    float v7 = W1[(kb + 19) * 256 + n] * TSCALE;
    int4v d = {pk2(v0, v1), pk2(v2, v3), pk2(v4, v5), pk2(v6, v7)};
    *(int4v*)(ldsb + W1F_OFF + pi * 16) = d;
  }
  // ---- stage W2 frags: fid = p*8 + tb ----
  #pragma unroll 1
  for (int it = 0; it < 16; it++) {
    const int pi = it * 256 + tid;
    const int fid = pi >> 6, L = pi & 63;
    const int p = fid >> 3, tb = fid & 7;
    const int lf = L & 15, qf = L >> 4;
    const int d_out = tb * 16 + lf;        // output-dim (A-frag m-row)
    const int kb = p * 32 + qf * 4;        // logical hid base
    float v0 = W2[(kb + 0) * 128 + d_out];
    float v1 = W2[(kb + 1) * 128 + d_out];
    float v2 = W2[(kb + 2) * 128 + d_out];
    float v3 = W2[(kb + 3) * 128 + d_out];
    float v4 = W2[(kb + 16) * 128 + d_out];
    float v5 = W2[(kb + 17) * 128 + d_out];
    float v6 = W2[(kb + 18) * 128 + d_out];
    float v7 = W2[(kb + 19) * 128 + d_out];
    int4v d = {pk2(v0, v1), pk2(v2, v3), pk2(v4, v5), pk2(v6, v7)};
    *(int4v*)(ldsb + W2F_OFF + pi * 16) = d;
  }
  b1f[tid] = b1[tid] * TSCALE;       // 256 threads == 256 entries
  if (tid < 50) dtf[tid] = ts[tid + 1] - ts[tid];

  // ---- b2 resident per-lane (C-layout columns) ----
  float4v b2v[8];
  #pragma unroll
  for (int tb = 0; tb < 8; tb++)
    b2v[tb] = *(const float4v*)&b2[tb * 16 + q * 4];

  // ---- load h for both groups ----
  float4v h4a[8], h4b[8];
  #pragma unroll
  for (int tb = 0; tb < 8; tb++) {
    h4a[tb] = *(const float4v*)&inp[rowa * 128 + tb * 16 + q * 4];
    h4b[tb] = *(const float4v*)&inp[rowb * 128 + tb * 16 + q * 4];
  }

  __syncthreads();  // the only barrier

  // per-lane frag base pointers
  const int4v* w1f = (const int4v*)(ldsb + W1F_OFF) + lane;
  const int4v* w2f = (const int4v*)(ldsb + W2F_OFF) + lane;

  #pragma unroll 1
  for (int s = 0; s < 50; s++) {
    const float dt = dtf[s];
    const float m2dt = -2.0f * dt;

    // ---- states -> B-frags (pure register packing) ----
    FB hba[4], hbb[4];
    #pragma unroll
    for (int kc = 0; kc < 4; kc++) {
      hba[kc].i = packfrag(h4a[2 * kc], h4a[2 * kc + 1]);
      hbb[kc].i = packfrag(h4b[2 * kc], h4b[2 * kc + 1]);
    }

    // ---- rotated depth-1 pipeline over 8 hid-pair chunks ----
    // prologue: mm1(0) both groups + act(0) -> afa, afb
    FB afa, afb;
    {
      FB wA[4], wB[4];
      #pragma unroll
      for (int c = 0; c < 4; c++) {
        wA[c].i = w1f[(0 * 4 + c) * 64];
        wB[c].i = w1f[(1 * 4 + c) * 64];
      }
      const float4v bi0 = *(const float4v*)&b1f[0 * 16 + q * 4];
      const float4v bi1 = *(const float4v*)&b1f[1 * 16 + q * 4];
      float4v g0a = bi0, g1a = bi1, g0b = bi0, g1b = bi1;
      #pragma unroll
      for (int c = 0; c < 4; c++) {
        g0a = MFMA16(wA[c].s, hba[c].s, g0a);
        g1a = MFMA16(wB[c].s, hba[c].s, g1a);
        g0b = MFMA16(wA[c].s, hbb[c].s, g0b);
        g1b = MFMA16(wB[c].s, hbb[c].s, g1b);
      }
      float4v a0a, a1a, a0b, a1b;
      #pragma unroll
      for (int r = 0; r < 4; r++) {
        a0a[r] = fmaf(__builtin_amdgcn_rcpf(__builtin_amdgcn_exp2f(g0a[r]) + 1.0f), m2dt, dt);
        a1a[r] = fmaf(__builtin_amdgcn_rcpf(__builtin_amdgcn_exp2f(g1a[r]) + 1.0f), m2dt, dt);
        a0b[r] = fmaf(__builtin_amdgcn_rcpf(__builtin_amdgcn_exp2f(g0b[r]) + 1.0f), m2dt, dt);
        a1b[r] = fmaf(__builtin_amdgcn_rcpf(__builtin_amdgcn_exp2f(g1b[r]) + 1.0f), m2dt, dt);
      }
      afa.i = packfrag(a0a, a1a);
      afb.i = packfrag(a0b, a1b);
    }

    // steady: per p issue loads ; mm1(p) both groups ; mm2(p-1) both ; act(p)
    #pragma unroll 1
    for (int p = 1; p < 8; p++) {
      const int nt0 = 2 * p, nt1 = 2 * p + 1;
      FB wA[4], wB[4];
      #pragma unroll
      for (int c = 0; c < 4; c++) {
        wA[c].i = w1f[(nt0 * 4 + c) * 64];
        wB[c].i = w1f[(nt1 * 4 + c) * 64];
      }
      FB w2r[8];
      #pragma unroll
      for (int tb = 0; tb < 8; tb++)
        w2r[tb].i = w2f[((p - 1) * 8 + tb) * 64];

      const float4v bi0 = *(const float4v*)&b1f[nt0 * 16 + q * 4];
      const float4v bi1 = *(const float4v*)&b1f[nt1 * 16 + q * 4];
      float4v g0a = bi0, g1a = bi1, g0b = bi0, g1b = bi1;
      #pragma unroll
      for (int c = 0; c < 4; c++) {
        g0a = MFMA16(wA[c].s, hba[c].s, g0a);
        g1a = MFMA16(wB[c].s, hba[c].s, g1a);
        g0b = MFMA16(wA[c].s, hbb[c].s, g0b);
        g1b = MFMA16(wB[c].s, hbb[c].s, g1b);
      }
      // mm2(p-1): consumes afa/afb from previous iteration
      #pragma unroll
      for (int tb = 0; tb < 8; tb++) {
        h4a[tb] = MFMA16(w2r[tb].s, afa.s, h4a[tb]);
        h4b[tb] = MFMA16(w2r[tb].s, afb.s, h4b[tb]);
      }
      // act(p): refill afa/afb
      float4v a0a, a1a, a0b, a1b;
      #pragma unroll
      for (int r = 0; r < 4; r++) {
        a0a[r] = fmaf(__builtin_amdgcn_rcpf(__builtin_amdgcn_exp2f(g0a[r]) + 1.0f), m2dt, dt);
        a1a[r] = fmaf(__builtin_amdgcn_rcpf(__builtin_amdgcn_exp2f(g1a[r]) + 1.0f), m2dt, dt);
        a0b[r] = fmaf(__builtin_amdgcn_rcpf(__builtin_amdgcn_exp2f(g0b[r]) + 1.0f), m2dt, dt);
        a1b[r] = fmaf(__builtin_amdgcn_rcpf(__builtin_amdgcn_exp2f(g1b[r]) + 1.0f), m2dt, dt);
      }
      afa.i = packfrag(a0a, a1a);
      afb.i = packfrag(a0b, a1b);
    }

    // epilogue: mm2(7) both groups
    {
      FB w2r[8];
      #pragma unroll
      for (int tb = 0; tb < 8; tb++)
        w2r[tb].i = w2f[(7 * 8 + tb) * 64];
      #pragma unroll
      for (int tb = 0; tb < 8; tb++) {
        h4a[tb] = MFMA16(w2r[tb].s, afa.s, h4a[tb]);
        h4b[tb] = MFMA16(w2r[tb].s, afb.s, h4b[tb]);
      }
    }

    // ---- h += dt * b2 ----
    #pragma unroll
    for (int tb = 0; tb < 8; tb++)
      #pragma unroll
      for (int r = 0; r < 4; r++) {
        h4a[tb][r] = fmaf(dt, b2v[tb][r], h4a[tb][r]);
        h4b[tb][r] = fmaf(dt, b2v[tb][r], h4b[tb][r]);
      }
  }

  // ---- store both groups ----
  #pragma unroll
  for (int tb = 0; tb < 8; tb++) {
    *(float4v*)&out[rowa * 128 + tb * 16 + q * 4] = h4a[tb];
    *(float4v*)&out[rowb * 128 + tb * 16 + q * 4] = h4b[tb];
  }
}

extern "C" void kernel_launch(void* const* d_in, const int* in_sizes, int n_in,
                              void* d_out, int out_size, void* d_ws, size_t ws_size,
                              hipStream_t stream) {
  const float* inp = (const float*)d_in[0];
  const float* ts  = (const float*)d_in[1];
  const float* W1  = (const float*)d_in[2];
  const float* b1  = (const float*)d_in[3];
  const float* W2  = (const float*)d_in[4];
  const float* b2  = (const float*)d_in[5];
  hipLaunchKernelGGL(ode_kernel, dim3(256), dim3(256), 0, stream,
                     inp, ts, W1, b1, W2, b2, (float*)d_out);
}